// Round 15
// baseline (159.414 us; speedup 1.0000x reference)
//
#include <hip/hip_runtime.h>
#include <math.h>

// Problem constants (fixed by the reference)
#define NQ   1024      // B*LT
#define DIM  512
#define NH   8
#define DHD  64
#define DFF  2048
#define LM   64        // LMEM
#define NMEM 1024

typedef __bf16 bf16x8 __attribute__((ext_vector_type(8)));
typedef float  f32x4  __attribute__((ext_vector_type(4)));
typedef float  f32x2v __attribute__((ext_vector_type(2)));

__device__ __forceinline__ unsigned short f2bf(float f) {
    unsigned u = __builtin_bit_cast(unsigned, f);
    return (unsigned short)((u + 0x7fffu + ((u >> 16) & 1u)) >> 16);
}
__device__ __forceinline__ float bflo(unsigned p) {
    return __builtin_bit_cast(float, p << 16);
}
__device__ __forceinline__ float bfhi(unsigned p) {
    return __builtin_bit_cast(float, p & 0xffff0000u);
}

__device__ __forceinline__ void gload16(const void* g, void* l) {
    __builtin_amdgcn_global_load_lds(
        (const __attribute__((address_space(1))) unsigned*)g,
        (__attribute__((address_space(3))) unsigned*)l, 16, 0, 0);
}

__device__ __forceinline__ float4 ntload4(const float4* p) {
    f32x4 v = __builtin_nontemporal_load((const f32x4*)p);
    return make_float4(v[0], v[1], v[2], v[3]);
}
__device__ __forceinline__ float2 ntload2(const float2* p) {
    f32x2v v = __builtin_nontemporal_load((const f32x2v*)p);
    return make_float2(v[0], v[1]);
}

// ---------------------------------------------------------------- helpers
__device__ __forceinline__ float blk_sum(float v, volatile float* red) {
#pragma unroll
    for (int o = 32; o; o >>= 1) v += __shfl_down(v, o);
    __syncthreads();
    if ((threadIdx.x & 63) == 0) red[threadIdx.x >> 6] = v;
    __syncthreads();
    return red[0] + red[1] + red[2] + red[3];
}

// ------------------------------------------------- K1: weight-prep + LN0 + argmax
struct PrepPtrs {
    const float* src[8];
    unsigned short* dst[8];
};
// blocks [0,5120): weight prep; blocks [5120,6144): LN0+argmax for n = bid-5120
__global__ __launch_bounds__(256) void prep_ln0_k(
    PrepPtrs p,
    const float* __restrict__ dec_out, const float* __restrict__ attn_out,
    const float* __restrict__ g, const float* __restrict__ be,
    float* __restrict__ x, unsigned* __restrict__ xb, int* __restrict__ samples)
{
    __shared__ float tile[32][33];
    __shared__ float red[4];
    __shared__ float rv[4]; __shared__ int ri[4];
    const int bid = blockIdx.x;

    if (bid < 5120) {
        int m, lt;
        if (bid < 1024) { m = bid >> 8; lt = bid & 255; }
        else { m = 4 + ((bid - 1024) >> 10); lt = (bid - 1024) & 1023; }
        const int RS = (m < 4) ? 512 : ((m == 5 || m == 7) ? 2048 : 512);
        const int CS = (m < 4) ? 512 : ((m == 5 || m == 7) ? 512 : 2048);
        const int TC = CS >> 5;
        const int tr = lt / TC, tc = lt % TC;
        const float* s = p.src[m];
        unsigned short* d = p.dst[m];
        const int tx = threadIdx.x & 31, ty = threadIdx.x >> 5;
        if (m == 1) {
#pragma unroll
            for (int i = 0; i < 32; i += 8) {
                size_t idx = (size_t)(tr * 32 + ty + i) * CS + tc * 32 + tx;
                d[idx] = f2bf(s[idx]);
            }
        } else {
#pragma unroll
            for (int i = 0; i < 32; i += 8)
                tile[ty + i][tx] = s[(size_t)(tr * 32 + ty + i) * CS + tc * 32 + tx];
            __syncthreads();
#pragma unroll
            for (int i = 0; i < 32; i += 8)
                d[(size_t)(tc * 32 + ty + i) * RS + tr * 32 + tx] = f2bf(tile[tx][ty + i]);
        }
        return;
    }

    const int n = bid - 5120, t = threadIdx.x;
    float2 v = ((const float2*)(dec_out + (size_t)n * DIM))[t];
    float mu  = blk_sum(v.x + v.y, red) * (1.f / DIM);
    float dx = v.x - mu, dy = v.y - mu;
    float var = blk_sum(dx * dx + dy * dy, red) * (1.f / DIM);
    float rs = rsqrtf(var + 1e-5f);
    float2 gg = ((const float2*)g)[t], bb = ((const float2*)be)[t];
    float ox = dx * rs * gg.x + bb.x, oy = dy * rs * gg.y + bb.y;
    ((float2*)(x + (size_t)n * DIM))[t] = make_float2(ox, oy);
    xb[(size_t)n * 256 + t] = (unsigned)f2bf(ox) | ((unsigned)f2bf(oy) << 16);

    const float* ar = attn_out + (size_t)n * 1025;
    float bv = -INFINITY; int bi = 0x7fffffff;
    for (int i = t; i < 1025; i += 256) {
        float val = ar[i];
        if (val > bv || (val == bv && i < bi)) { bv = val; bi = i; }
    }
#pragma unroll
    for (int o = 32; o; o >>= 1) {
        float ov = __shfl_down(bv, o); int oi = __shfl_down(bi, o);
        if (ov > bv || (ov == bv && oi < bi)) { bv = ov; bi = oi; }
    }
    if ((t & 63) == 0) { rv[t >> 6] = bv; ri[t >> 6] = bi; }
    __syncthreads();
    if (t == 0) {
#pragma unroll
        for (int w = 1; w < 4; ++w)
            if (rv[w] > bv || (rv[w] == bv && ri[w] < bi)) { bv = rv[w]; bi = ri[w]; }
        samples[n] = bi - 1;
    }
}

// ------------------------------------------------- K2: build same-memory query pairs
__global__ __launch_bounds__(1024) void group_build_k(
    const int* __restrict__ samples, int2* __restrict__ plist,
    int* __restrict__ npairs)
{
    __shared__ int cnt[NMEM];
    __shared__ int base[NMEM];
    __shared__ int qls[NQ];
    __shared__ int wsum[16];
    __shared__ int wsum2[16];
    const int t = threadIdx.x;
    const int lane = t & 63, w = t >> 6;
    cnt[t] = 0;
    __syncthreads();
    int s = samples[t]; if (s < 0) s = 0;
    atomicAdd(&cnt[s], 1);
    __syncthreads();
    const int c = cnt[t];
    // scan 1: query-list offsets
    int v = c;
#pragma unroll
    for (int o = 1; o < 64; o <<= 1) {
        int u = __shfl_up(v, o);
        if (lane >= o) v += u;
    }
    if (lane == 63) wsum[w] = v;
    __syncthreads();
    if (w == 0) {
        int x = (lane < 16) ? wsum[lane] : 0;
#pragma unroll
        for (int o = 1; o < 16; o <<= 1) {
            int u = __shfl_up(x, o);
            if (lane >= o) x += u;
        }
        if (lane < 16) wsum[lane] = x;
    }
    __syncthreads();
    const int start = v - c + (w ? wsum[w - 1] : 0);
    base[t] = start;
    __syncthreads();
    cnt[t] = 0;
    __syncthreads();
    int pos = atomicAdd(&cnt[s], 1);
    qls[base[s] + pos] = t;
    // scan 2: pair offsets
    const int pc = (c + 1) >> 1;
    int pv = pc;
#pragma unroll
    for (int o = 1; o < 64; o <<= 1) {
        int u = __shfl_up(pv, o);
        if (lane >= o) pv += u;
    }
    if (lane == 63) wsum2[w] = pv;
    __syncthreads();
    if (w == 0) {
        int x = (lane < 16) ? wsum2[lane] : 0;
#pragma unroll
        for (int o = 1; o < 16; o <<= 1) {
            int u = __shfl_up(x, o);
            if (lane >= o) x += u;
        }
        if (lane < 16) wsum2[lane] = x;
    }
    __syncthreads();
    const int pstart = pv - pc + (w ? wsum2[w - 1] : 0);
    if (t == NMEM - 1) *npairs = pstart + pc;
    __syncthreads();   // qls complete
    const int b = base[t];
    for (int j = 0; j < pc; ++j) {
        int qa = qls[b + 2 * j];
        int qb = (2 * j + 1 < c) ? qls[b + 2 * j + 1] : qa;
        plist[pstart + j] = make_int2(qa, qb);
    }
}

// ------------------------------------------------- bf16 MFMA GEMM, 64x64 tile
// XCD-aware tile swizzle: requires gridDim.x*gridDim.y % 8 == 0.
template<bool RELU, bool BIAS, bool RES, bool WF32, bool WBF>
__global__ __launch_bounds__(256) void mfma_gemm(
    const unsigned short* __restrict__ A, const unsigned short* __restrict__ Bt,
    float* __restrict__ Cf, unsigned short* __restrict__ Cb,
    const float* __restrict__ bias, const float* __restrict__ res,
    int K, int lda, int ldb, int ldc,
    int sA, int sB, int sC, int sBias)
{
    __shared__ unsigned short Ab[2][64 * 64];
    __shared__ unsigned short Bb[2][64 * 64];
    const int t = threadIdx.x, lane = t & 63, wid = t >> 6;
    const int nx = gridDim.x;
    const int fid = blockIdx.y * nx + blockIdx.x;
    const int cpx = (nx * gridDim.y) >> 3;
    const int f2 = (fid & 7) * cpx + (fid >> 3);
    const int bn = (f2 % nx) * 64, bm = (f2 / nx) * 64, bz = blockIdx.z;
    const unsigned short* Abase = A + (size_t)bz * sA + (size_t)bm * lda;
    const unsigned short* Bbase = Bt + (size_t)bz * sB + (size_t)bn * ldb;

    const int r0 = wid * 16 + (lane >> 3);
    const int cbs = lane & 7;

#define STAGE_T(buf, base, ld, kt)                                              \
    {                                                                           \
        int r_ = r0;                                                            \
        gload16(base + (size_t)r_ * ld + (kt) * 64 + ((cbs ^ (r_ & 7)) << 3),   \
                &buf[(wid * 2 + 0) * 512]);                                     \
        r_ = r0 + 8;                                                            \
        gload16(base + (size_t)r_ * ld + (kt) * 64 + ((cbs ^ (r_ & 7)) << 3),   \
                &buf[(wid * 2 + 1) * 512]);                                     \
    }

    const int lr = lane & 15, lg = lane >> 4;
    const int wr = (wid >> 1) * 32, wc = (wid & 1) * 32;
    const int mA0 = wr + lr, mA1 = wr + 16 + lr;
    const int nB0 = wc + lr, nB1 = wc + 16 + lr;
    f32x4 acc[2][2] = {};

#define COMPUTE(b)                                                              \
    _Pragma("unroll")                                                           \
    for (int kk = 0; kk < 2; ++kk) {                                            \
        const int kb = kk * 4 + lg;                                             \
        bf16x8 a0 = *(const bf16x8*)&Ab[b][mA0 * 64 + ((kb ^ (mA0 & 7)) << 3)]; \
        bf16x8 a1 = *(const bf16x8*)&Ab[b][mA1 * 64 + ((kb ^ (mA1 & 7)) << 3)]; \
        bf16x8 b0 = *(const bf16x8*)&Bb[b][nB0 * 64 + ((kb ^ (nB0 & 7)) << 3)]; \
        bf16x8 b1 = *(const bf16x8*)&Bb[b][nB1 * 64 + ((kb ^ (nB1 & 7)) << 3)]; \
        acc[0][0] = __builtin_amdgcn_mfma_f32_16x16x32_bf16(a0, b0, acc[0][0], 0, 0, 0); \
        acc[0][1] = __builtin_amdgcn_mfma_f32_16x16x32_bf16(a0, b1, acc[0][1], 0, 0, 0); \
        acc[1][0] = __builtin_amdgcn_mfma_f32_16x16x32_bf16(a1, b0, acc[1][0], 0, 0, 0); \
        acc[1][1] = __builtin_amdgcn_mfma_f32_16x16x32_bf16(a1, b1, acc[1][1], 0, 0, 0); \
    }

    STAGE_T(Ab[0], Abase, lda, 0);
    STAGE_T(Bb[0], Bbase, ldb, 0);
    __syncthreads();
    const int NT = K >> 6;
    int cur = 0;
    for (int kt = 0; kt < NT; ++kt) {
        if (kt + 1 < NT) {
            STAGE_T(Ab[cur ^ 1], Abase, lda, kt + 1);
            STAGE_T(Bb[cur ^ 1], Bbase, ldb, kt + 1);
        }
        if (cur == 0) { COMPUTE(0); } else { COMPUTE(1); }
        __syncthreads();
        cur ^= 1;
    }

#pragma unroll
    for (int fm = 0; fm < 2; ++fm)
#pragma unroll
    for (int fn = 0; fn < 2; ++fn) {
        const int col = bn + wc + fn * 16 + lr;
        float bia = BIAS ? bias[bz * sBias + col] : 0.f;
#pragma unroll
        for (int r = 0; r < 4; ++r) {
            const int row = bm + wr + fm * 16 + lg * 4 + r;
            const size_t ci = (size_t)bz * sC + (size_t)row * ldc + col;
            float v = acc[fm][fn][r] + bia;
            if (RES) v += res[(size_t)row * ldc + col];
            if (RELU) v = fmaxf(v, 0.f);
            if (WF32) Cf[ci] = v;
            if (WBF)  Cb[ci] = f2bf(v);
        }
    }
#undef STAGE_T
#undef COMPUTE
}

// ------------------------------------------------- K5: fused attention, query-paired
// Block = one pair (qa,qb) sharing memory s. Waves 0-3: scores MFMA (16 B-cols =
// {qa h0-7, qb h0-7}, 8-deep nt prefetch) + softmax. Waves 4-7: PV (nt float2
// V stream, 8-deep, prefetched concurrently with scores).
__global__ __launch_bounds__(512) void attn_fused_k(
    const unsigned short* __restrict__ u_bf, const float* __restrict__ enc,
    const float* __restrict__ vemb, const int* __restrict__ maskmem,
    const int* __restrict__ samples, const int2* __restrict__ plist,
    const int* __restrict__ npairs, unsigned* __restrict__ a_bf)
{
    __shared__ float S_lds[16 * 68];
    __shared__ uint4 P_lds[2][64];    // [query][key] -> 8 heads bf16
    __shared__ int Msk_lds[64];
    const int pid = blockIdx.x;
    if (pid >= *npairs) return;
    const int2 pq = plist[pid];
    const int qa = pq.x, qb = pq.y;
    int s = samples[qa]; if (s < 0) s = 0;
    const int t = threadIdx.x, lane = t & 63, w = t >> 6;

    float2 pfv[8];
    const float2* vb = (const float2*)(vemb + (size_t)s * (LM * DIM)) + (t - 256);

    if (w >= 4) {
        // PV waves: thread owns dim-pair (t-256); prefetch keys 0..7 (nt)
#pragma unroll
        for (int i = 0; i < 8; ++i) pfv[i] = ntload2(vb + (size_t)i * 256);
        if (w == 4) Msk_lds[lane] = maskmem[(size_t)s * LM + lane];
    } else {
        // scores waves: wave w -> keys [w*16, w*16+16), K=512 in 16 steps, 8-deep nt prefetch
        const float4* kb = (const float4*)(enc + (size_t)s * (LM * DIM));
        const int key = w * 16 + (lane & 15);
        const int lg = lane >> 4;
        const int h = lane & 15;
        const int base = key * 128 + lg * 2;  // float4 units
        float4 pf[8][2];
#pragma unroll
        for (int ss = 0; ss < 8; ++ss) {
            pf[ss][0] = ntload4(kb + base + ss * 8);
            pf[ss][1] = ntload4(kb + base + ss * 8 + 1);
        }
        const int qsel = (h < 8) ? qa : qb;
        const unsigned short* ub = u_bf + (size_t)qsel * 4096 + (size_t)(h & 7) * 512;
        f32x4 acc = {};
#pragma unroll
        for (int step = 0; step < 16; ++step) {
            float4 a0 = pf[step & 7][0], a1 = pf[step & 7][1];
            if (step + 8 < 16) {
                pf[step & 7][0] = ntload4(kb + base + (step + 8) * 8);
                pf[step & 7][1] = ntload4(kb + base + (step + 8) * 8 + 1);
            }
            bf16x8 af;
            af[0] = (__bf16)a0.x; af[1] = (__bf16)a0.y;
            af[2] = (__bf16)a0.z; af[3] = (__bf16)a0.w;
            af[4] = (__bf16)a1.x; af[5] = (__bf16)a1.y;
            af[6] = (__bf16)a1.z; af[7] = (__bf16)a1.w;
            bf16x8 bfr = *(const bf16x8*)&ub[(step * 4 + lg) * 8];
            acc = __builtin_amdgcn_mfma_f32_16x16x32_bf16(af, bfr, acc, 0, 0, 0);
        }
#pragma unroll
        for (int r = 0; r < 4; ++r)
            S_lds[h * 68 + w * 16 + lg * 4 + r] = acc[r];
    }
    __syncthreads();   // S_lds + Msk ready

    if (w < 4) {
        // softmax: 16 slots (2 queries x 8 heads); wave w -> slots w, w+4, w+8, w+12
#pragma unroll
        for (int i = 0; i < 4; ++i) {
            const int slot = w + i * 4;
            const int qq = slot >> 3, h2 = slot & 7;
            float sc = S_lds[slot * 68 + lane] * 0.125f;
            sc = (Msk_lds[lane] != 0) ? sc : -1e9f;
            float m = sc;
#pragma unroll
            for (int o = 32; o; o >>= 1) m = fmaxf(m, __shfl_xor(m, o));
            float e = __expf(sc - m);
            float su = e;
#pragma unroll
            for (int o = 32; o; o >>= 1) su += __shfl_xor(su, o);
            ((unsigned short*)P_lds)[(qq * 64 + lane) * 8 + h2] = f2bf(e / su);
        }
    }
    __syncthreads();   // P ready

    if (w >= 4) {
        float2 accA[8], accB[8];
#pragma unroll
        for (int hh = 0; hh < 8; ++hh) {
            accA[hh] = make_float2(0.f, 0.f);
            accB[hh] = make_float2(0.f, 0.f);
        }
#pragma unroll 8
        for (int k = 0; k < 64; ++k) {
            float2 v = pfv[k & 7];
            if (k + 8 < 64) pfv[k & 7] = ntload2(vb + (size_t)(k + 8) * 256);
            uint4 pa = P_lds[0][k];
            uint4 pb = P_lds[1][k];
            float a0 = bflo(pa.x), a1 = bfhi(pa.x), a2 = bflo(pa.y), a3 = bfhi(pa.y);
            float a4 = bflo(pa.z), a5 = bfhi(pa.z), a6 = bflo(pa.w), a7 = bfhi(pa.w);
            float b0 = bflo(pb.x), b1 = bfhi(pb.x), b2 = bflo(pb.y), b3 = bfhi(pb.y);
            float b4 = bflo(pb.z), b5 = bfhi(pb.z), b6 = bflo(pb.w), b7 = bfhi(pb.w);
            accA[0].x = fmaf(a0, v.x, accA[0].x); accA[0].y = fmaf(a0, v.y, accA[0].y);
            accA[1].x = fmaf(a1, v.x, accA[1].x); accA[1].y = fmaf(a1, v.y, accA[1].y);
            accA[2].x = fmaf(a2, v.x, accA[2].x); accA[2].y = fmaf(a2, v.y, accA[2].y);
            accA[3].x = fmaf(a3, v.x, accA[3].x); accA[3].y = fmaf(a3, v.y, accA[3].y);
            accA[4].x = fmaf(a4, v.x, accA[4].x); accA[4].y = fmaf(a4, v.y, accA[4].y);
            accA[5].x = fmaf(a5, v.x, accA[5].x); accA[5].y = fmaf(a5, v.y, accA[5].y);
            accA[6].x = fmaf(a6, v.x, accA[6].x); accA[6].y = fmaf(a6, v.y, accA[6].y);
            accA[7].x = fmaf(a7, v.x, accA[7].x); accA[7].y = fmaf(a7, v.y, accA[7].y);
            accB[0].x = fmaf(b0, v.x, accB[0].x); accB[0].y = fmaf(b0, v.y, accB[0].y);
            accB[1].x = fmaf(b1, v.x, accB[1].x); accB[1].y = fmaf(b1, v.y, accB[1].y);
            accB[2].x = fmaf(b2, v.x, accB[2].x); accB[2].y = fmaf(b2, v.y, accB[2].y);
            accB[3].x = fmaf(b3, v.x, accB[3].x); accB[3].y = fmaf(b3, v.y, accB[3].y);
            accB[4].x = fmaf(b4, v.x, accB[4].x); accB[4].y = fmaf(b4, v.y, accB[4].y);
            accB[5].x = fmaf(b5, v.x, accB[5].x); accB[5].y = fmaf(b5, v.y, accB[5].y);
            accB[6].x = fmaf(b6, v.x, accB[6].x); accB[6].y = fmaf(b6, v.y, accB[6].y);
            accB[7].x = fmaf(b7, v.x, accB[7].x); accB[7].y = fmaf(b7, v.y, accB[7].y);
        }
        unsigned* an = a_bf + (size_t)qa * 2048 + (t - 256);
#pragma unroll
        for (int hh = 0; hh < 8; ++hh)
            an[hh * 256] = (unsigned)f2bf(accA[hh].x) | ((unsigned)f2bf(accA[hh].y) << 16);
        if (qb != qa) {
            unsigned* bn2 = a_bf + (size_t)qb * 2048 + (t - 256);
#pragma unroll
            for (int hh = 0; hh < 8; ++hh)
                bn2[hh * 256] = (unsigned)f2bf(accB[hh].x) | ((unsigned)f2bf(accB[hh].y) << 16);
        }
    }
}

// ------------------------------------------------- K10: combine T1 parts + LN + mask + x
__global__ __launch_bounds__(256) void ln1_mask_add_k(
    const float* __restrict__ t1p, const float* __restrict__ st0,
    const float* __restrict__ b2, const float* __restrict__ g,
    const float* __restrict__ be, const int* __restrict__ samples,
    const float* __restrict__ x, float* __restrict__ dec, unsigned* __restrict__ decb)
{
    __shared__ float red[4];
    const int n = blockIdx.x, t = threadIdx.x;
    const size_t off = (size_t)n * DIM + t * 2;
    float2 p0 = *(const float2*)&t1p[off];
    float2 p1 = *(const float2*)&t1p[(size_t)NQ * DIM + off];
    float2 s0 = *(const float2*)&st0[off];
    float2 b2v = ((const float2*)b2)[t];
    float2 v = make_float2(p0.x + p1.x + s0.x + b2v.x, p0.y + p1.y + s0.y + b2v.y);
    float mu  = blk_sum(v.x + v.y, red) * (1.f / DIM);
    float dx = v.x - mu, dy = v.y - mu;
    float var = blk_sum(dx * dx + dy * dy, red) * (1.f / DIM);
    float rs = rsqrtf(var + 1e-5f);
    float2 gg = ((const float2*)g)[t], bb = ((const float2*)be)[t];
    float sx = dx * rs * gg.x + bb.x, sy = dy * rs * gg.y + bb.y;
    if (samples[n] < 0) { sx = 0.f; sy = 0.f; }
    float2 xx = *(const float2*)&x[off];
    float ox = xx.x + sx, oy = xx.y + sy;
    *(float2*)&dec[off] = make_float2(ox, oy);
    decb[(size_t)n * 256 + t] = (unsigned)f2bf(ox) | ((unsigned)f2bf(oy) << 16);
}

// ---------------------------------------------------------------- launcher
extern "C" void kernel_launch(void* const* d_in, const int* in_sizes, int n_in,
                              void* d_out, int out_size, void* d_ws, size_t ws_size,
                              hipStream_t stream)
{
    const float* dec_output = (const float*)d_in[0];
    const float* mem_attn   = (const float*)d_in[1];
    const float* enc_mem    = (const float*)d_in[2];
    const float* temb_mem   = (const float*)d_in[3];
    const int*   mask_mem   = (const int*)d_in[4];
    const float* g0  = (const float*)d_in[6];
    const float* be0 = (const float*)d_in[7];
    const float* g1  = (const float*)d_in[8];
    const float* be1 = (const float*)d_in[9];
    const float* Wq  = (const float*)d_in[10];
    const float* bq  = (const float*)d_in[11];
    const float* Wk  = (const float*)d_in[12];
    const float* Wv  = (const float*)d_in[14];
    const float* bv  = (const float*)d_in[15];
    const float* Wo  = (const float*)d_in[16];
    const float* bo  = (const float*)d_in[17];
    const float* f1W1 = (const float*)d_in[18];
    const float* f1b1 = (const float*)d_in[19];
    const float* f1W2 = (const float*)d_in[20];
    const float* f1b2 = (const float*)d_in[21];
    const float* f2W1 = (const float*)d_in[22];
    const float* f2b1 = (const float*)d_in[23];
    const float* f2W2 = (const float*)d_in[24];
    const float* f2b2 = (const float*)d_in[25];
    float* out = (float*)d_out;

    float* ws = (float*)d_ws;
    // persistent (offsets in floats)
    float*          x_f   = ws + 0;                          // 524288
    unsigned*       x_b   = (unsigned*)(ws + 524288);        // 262144
    unsigned short* qh_b  = (unsigned short*)(ws + 786432);  // 262144
    unsigned short* u_b   = (unsigned short*)(ws + 1048576); // 2097152
    unsigned short* a_b   = (unsigned short*)(ws + 3145728); // 2097152
    unsigned short* wqt   = (unsigned short*)(ws + 7340032); // 131072 each
    unsigned short* wkc   = (unsigned short*)(ws + 7471104);
    unsigned short* wvt   = (unsigned short*)(ws + 7602176);
    unsigned short* wot   = (unsigned short*)(ws + 7733248);
    unsigned short* f1w1t = (unsigned short*)(ws + 7864320); // 524288 each
    unsigned short* f1w2t = (unsigned short*)(ws + 8388608);
    unsigned short* f2w1t = (unsigned short*)(ws + 8912896);
    unsigned short* f2w2t = (unsigned short*)(ws + 9437184);
    int*            smp   = (int*)(ws + 9961472);            // 1024
    float*          t1p_f = ws + 9962496;                    // 1048576 (2 parts)
    int2*           plist = (int2*)(ws + 11011072);          // 1024 int2
    int*            npair = (int*)(ws + 11013120);           // 1
    // aliases inside u_b region (u dead after attn_fused):
    float*          st0_f = (float*)u_b + 0;                 // 524288
    unsigned short* st0_b = (unsigned short*)((float*)u_b + 524288); // 131072
    float*          dec_f = (float*)u_b + 655360;            // 524288
    unsigned*       dec_b = (unsigned*)((float*)u_b + 1179648); // 131072
    // aliases inside a_b region (a dead after CTX GEMM):
    unsigned short* h1_b  = a_b;                             // 1024x2048 bf16
    unsigned short* h2_b  = (unsigned short*)((float*)a_b + 1048576);

    PrepPtrs pp;
    pp.src[0] = Wq;   pp.dst[0] = wqt;
    pp.src[1] = Wk;   pp.dst[1] = wkc;
    pp.src[2] = Wv;   pp.dst[2] = wvt;
    pp.src[3] = Wo;   pp.dst[3] = wot;
    pp.src[4] = f1W1; pp.dst[4] = f1w1t;
    pp.src[5] = f1W2; pp.dst[5] = f1w2t;
    pp.src[6] = f2W1; pp.dst[6] = f2w1t;
    pp.src[7] = f2W2; pp.dst[7] = f2w2t;
    // 1. weight prep + LN0 + argmax
    prep_ln0_k<<<5120 + NQ, 256, 0, stream>>>(pp, dec_output, mem_attn, g0, be0,
                                              x_f, x_b, smp);
    // 2. build same-memory query pairs
    group_build_k<<<1, 1024, 0, stream>>>(smp, plist, npair);
    // 3. QH = X @ Wq + bq  (bf16 out only)
    mfma_gemm<false, true, false, false, true><<<dim3(8, 16, 1), 256, 0, stream>>>(
        (const unsigned short*)x_b, wqt, nullptr, qh_b, bq, nullptr,
        DIM, DIM, DIM, DIM, 0, 0, 0, 0);
    // 4. U_h = QH_h @ Wk_h^T (batched heads, K=64)
    mfma_gemm<false, false, false, false, true><<<dim3(8, 16, NH), 256, 0, stream>>>(
        qh_b, wkc, nullptr, u_b, nullptr, nullptr,
        DHD, DIM, DIM, NH * DIM, DHD, DHD, DIM, 0);
    // 5. fused attention (query-paired; scores + softmax + PV, wave-specialized)
    attn_fused_k<<<NQ, 512, 0, stream>>>(u_b, enc_mem, temb_mem, mask_mem, smp,
                                         plist, npair, (unsigned*)a_b);
    // 6. CTX_h = A_h @ Wv_h + bv_h
    mfma_gemm<false, true, false, false, true><<<dim3(1, 16, NH), 256, 0, stream>>>(
        a_b, wvt, nullptr, qh_b, bv, nullptr,
        DIM, NH * DIM, DIM, DIM, DIM, DHD * DIM, DHD, DHD);
    // 7. ST0 = X + CTX @ Wo + bo
    mfma_gemm<false, true, true, true, true><<<dim3(8, 16, 1), 256, 0, stream>>>(
        qh_b, wot, st0_f, st0_b, bo, x_f, DIM, DIM, DIM, DIM, 0, 0, 0, 0);
    // 8. H1 = relu(ST0 @ f1W1 + f1b1)
    mfma_gemm<true, true, false, false, true><<<dim3(32, 16, 1), 256, 0, stream>>>(
        st0_b, f1w1t, nullptr, h1_b, f1b1, nullptr, DIM, DIM, DIM, DFF, 0, 0, 0, 0);
    // 9. T1 parts = H1 @ f1W2 (split-K=2; bias/res merged in LN1)
    mfma_gemm<false, false, false, true, false><<<dim3(8, 16, 2), 256, 0, stream>>>(
        h1_b, f1w2t, t1p_f, nullptr, nullptr, nullptr,
        1024, DFF, DFF, DIM, 1024, 1024, NQ * DIM, 0);
    // 10. DEC = X + mask * LN1(p0 + p1 + ST0 + f1b2)
    ln1_mask_add_k<<<NQ, 256, 0, stream>>>(t1p_f, st0_f, f1b2, g1, be1, smp,
                                           x_f, dec_f, dec_b);
    // 11. H2 = relu(DEC @ f2W1 + f2b1)
    mfma_gemm<true, true, false, false, true><<<dim3(32, 16, 1), 256, 0, stream>>>(
        (const unsigned short*)dec_b, f2w1t, nullptr, h2_b, f2b1, nullptr,
        DIM, DIM, DIM, DFF, 0, 0, 0, 0);
    // 12. OUT = DEC + H2 @ f2W2 + f2b2
    mfma_gemm<false, true, true, true, false><<<dim3(8, 16, 1), 256, 0, stream>>>(
        h2_b, f2w2t, out, nullptr, f2b2, dec_f, DFF, DFF, DFF, DIM, 0, 0, 0, 0);

    (void)in_sizes; (void)n_in; (void)out_size; (void)ws_size;
}

// Round 16
// 148.901 us; speedup vs baseline: 1.0706x; 1.0706x over previous
//
#include <hip/hip_runtime.h>
#include <math.h>

// Problem constants (fixed by the reference)
#define NQ   1024      // B*LT
#define DIM  512
#define NH   8
#define DHD  64
#define DFF  2048
#define LM   64        // LMEM
#define NMEM 1024

typedef __bf16 bf16x8 __attribute__((ext_vector_type(8)));
typedef float  f32x4  __attribute__((ext_vector_type(4)));

__device__ __forceinline__ unsigned short f2bf(float f) {
    unsigned u = __builtin_bit_cast(unsigned, f);
    return (unsigned short)((u + 0x7fffu + ((u >> 16) & 1u)) >> 16);
}
__device__ __forceinline__ float bflo(unsigned p) {
    return __builtin_bit_cast(float, p << 16);
}
__device__ __forceinline__ float bfhi(unsigned p) {
    return __builtin_bit_cast(float, p & 0xffff0000u);
}

__device__ __forceinline__ void gload16(const void* g, void* l) {
    __builtin_amdgcn_global_load_lds(
        (const __attribute__((address_space(1))) unsigned*)g,
        (__attribute__((address_space(3))) unsigned*)l, 16, 0, 0);
}

// ---------------------------------------------------------------- helpers
__device__ __forceinline__ float blk_sum(float v, volatile float* red) {
#pragma unroll
    for (int o = 32; o; o >>= 1) v += __shfl_down(v, o);
    __syncthreads();
    if ((threadIdx.x & 63) == 0) red[threadIdx.x >> 6] = v;
    __syncthreads();
    return red[0] + red[1] + red[2] + red[3];
}

// ------------------------------------------------- K1: weight-prep + LN0 + argmax
struct PrepPtrs {
    const float* src[8];
    unsigned short* dst[8];
};
// blocks [0,5120): weight prep; blocks [5120,6144): LN0+argmax for n = bid-5120
__global__ __launch_bounds__(256) void prep_ln0_k(
    PrepPtrs p,
    const float* __restrict__ dec_out, const float* __restrict__ attn_out,
    const float* __restrict__ g, const float* __restrict__ be,
    float* __restrict__ x, unsigned* __restrict__ xb, int* __restrict__ samples)
{
    __shared__ float tile[32][33];
    __shared__ float red[4];
    __shared__ float rv[4]; __shared__ int ri[4];
    const int bid = blockIdx.x;

    if (bid < 5120) {
        int m, lt;
        if (bid < 1024) { m = bid >> 8; lt = bid & 255; }
        else { m = 4 + ((bid - 1024) >> 10); lt = (bid - 1024) & 1023; }
        const int RS = (m < 4) ? 512 : ((m == 5 || m == 7) ? 2048 : 512);
        const int CS = (m < 4) ? 512 : ((m == 5 || m == 7) ? 512 : 2048);
        const int TC = CS >> 5;
        const int tr = lt / TC, tc = lt % TC;
        const float* s = p.src[m];
        unsigned short* d = p.dst[m];
        const int tx = threadIdx.x & 31, ty = threadIdx.x >> 5;
        if (m == 1) {
#pragma unroll
            for (int i = 0; i < 32; i += 8) {
                size_t idx = (size_t)(tr * 32 + ty + i) * CS + tc * 32 + tx;
                d[idx] = f2bf(s[idx]);
            }
        } else {
#pragma unroll
            for (int i = 0; i < 32; i += 8)
                tile[ty + i][tx] = s[(size_t)(tr * 32 + ty + i) * CS + tc * 32 + tx];
            __syncthreads();
#pragma unroll
            for (int i = 0; i < 32; i += 8)
                d[(size_t)(tc * 32 + ty + i) * RS + tr * 32 + tx] = f2bf(tile[tx][ty + i]);
        }
        return;
    }

    const int n = bid - 5120, t = threadIdx.x;
    float2 v = ((const float2*)(dec_out + (size_t)n * DIM))[t];
    float mu  = blk_sum(v.x + v.y, red) * (1.f / DIM);
    float dx = v.x - mu, dy = v.y - mu;
    float var = blk_sum(dx * dx + dy * dy, red) * (1.f / DIM);
    float rs = rsqrtf(var + 1e-5f);
    float2 gg = ((const float2*)g)[t], bb = ((const float2*)be)[t];
    float ox = dx * rs * gg.x + bb.x, oy = dy * rs * gg.y + bb.y;
    ((float2*)(x + (size_t)n * DIM))[t] = make_float2(ox, oy);
    xb[(size_t)n * 256 + t] = (unsigned)f2bf(ox) | ((unsigned)f2bf(oy) << 16);

    const float* ar = attn_out + (size_t)n * 1025;
    float bv = -INFINITY; int bi = 0x7fffffff;
    for (int i = t; i < 1025; i += 256) {
        float val = ar[i];
        if (val > bv || (val == bv && i < bi)) { bv = val; bi = i; }
    }
#pragma unroll
    for (int o = 32; o; o >>= 1) {
        float ov = __shfl_down(bv, o); int oi = __shfl_down(bi, o);
        if (ov > bv || (ov == bv && oi < bi)) { bv = ov; bi = oi; }
    }
    if ((t & 63) == 0) { rv[t >> 6] = bv; ri[t >> 6] = bi; }
    __syncthreads();
    if (t == 0) {
#pragma unroll
        for (int w = 1; w < 4; ++w)
            if (rv[w] > bv || (rv[w] == bv && ri[w] < bi)) { bv = rv[w]; bi = ri[w]; }
        samples[n] = bi - 1;
    }
}

// ------------------------------------------------- K2: build same-memory query pairs
__global__ __launch_bounds__(1024) void group_build_k(
    const int* __restrict__ samples, int2* __restrict__ plist,
    int* __restrict__ npairs)
{
    __shared__ int cnt[NMEM];
    __shared__ int base[NMEM];
    __shared__ int qls[NQ];
    __shared__ int wsum[16];
    __shared__ int wsum2[16];
    const int t = threadIdx.x;
    const int lane = t & 63, w = t >> 6;
    cnt[t] = 0;
    __syncthreads();
    int s = samples[t]; if (s < 0) s = 0;
    atomicAdd(&cnt[s], 1);
    __syncthreads();
    const int c = cnt[t];
    // scan 1: query-list offsets
    int v = c;
#pragma unroll
    for (int o = 1; o < 64; o <<= 1) {
        int u = __shfl_up(v, o);
        if (lane >= o) v += u;
    }
    if (lane == 63) wsum[w] = v;
    __syncthreads();
    if (w == 0) {
        int x = (lane < 16) ? wsum[lane] : 0;
#pragma unroll
        for (int o = 1; o < 16; o <<= 1) {
            int u = __shfl_up(x, o);
            if (lane >= o) x += u;
        }
        if (lane < 16) wsum[lane] = x;
    }
    __syncthreads();
    const int start = v - c + (w ? wsum[w - 1] : 0);
    base[t] = start;
    __syncthreads();
    cnt[t] = 0;
    __syncthreads();
    int pos = atomicAdd(&cnt[s], 1);
    qls[base[s] + pos] = t;
    // scan 2: pair offsets
    const int pc = (c + 1) >> 1;
    int pv = pc;
#pragma unroll
    for (int o = 1; o < 64; o <<= 1) {
        int u = __shfl_up(pv, o);
        if (lane >= o) pv += u;
    }
    if (lane == 63) wsum2[w] = pv;
    __syncthreads();
    if (w == 0) {
        int x = (lane < 16) ? wsum2[lane] : 0;
#pragma unroll
        for (int o = 1; o < 16; o <<= 1) {
            int u = __shfl_up(x, o);
            if (lane >= o) x += u;
        }
        if (lane < 16) wsum2[lane] = x;
    }
    __syncthreads();
    const int pstart = pv - pc + (w ? wsum2[w - 1] : 0);
    if (t == NMEM - 1) *npairs = pstart + pc;
    __syncthreads();   // qls complete
    const int b = base[t];
    for (int j = 0; j < pc; ++j) {
        int qa = qls[b + 2 * j];
        int qb = (2 * j + 1 < c) ? qls[b + 2 * j + 1] : qa;
        plist[pstart + j] = make_int2(qa, qb);
    }
}

// ------------------------------------------------- bf16 MFMA GEMM, 64x64 tile
// XCD-aware tile swizzle: requires gridDim.x*gridDim.y % 8 == 0.
template<bool RELU, bool BIAS, bool RES, bool WF32, bool WBF>
__global__ __launch_bounds__(256) void mfma_gemm(
    const unsigned short* __restrict__ A, const unsigned short* __restrict__ Bt,
    float* __restrict__ Cf, unsigned short* __restrict__ Cb,
    const float* __restrict__ bias, const float* __restrict__ res,
    int K, int lda, int ldb, int ldc,
    int sA, int sB, int sC, int sBias)
{
    __shared__ unsigned short Ab[2][64 * 64];
    __shared__ unsigned short Bb[2][64 * 64];
    const int t = threadIdx.x, lane = t & 63, wid = t >> 6;
    const int nx = gridDim.x;
    const int fid = blockIdx.y * nx + blockIdx.x;
    const int cpx = (nx * gridDim.y) >> 3;
    const int f2 = (fid & 7) * cpx + (fid >> 3);
    const int bn = (f2 % nx) * 64, bm = (f2 / nx) * 64, bz = blockIdx.z;
    const unsigned short* Abase = A + (size_t)bz * sA + (size_t)bm * lda;
    const unsigned short* Bbase = Bt + (size_t)bz * sB + (size_t)bn * ldb;

    const int r0 = wid * 16 + (lane >> 3);
    const int cbs = lane & 7;

#define STAGE_T(buf, base, ld, kt)                                              \
    {                                                                           \
        int r_ = r0;                                                            \
        gload16(base + (size_t)r_ * ld + (kt) * 64 + ((cbs ^ (r_ & 7)) << 3),   \
                &buf[(wid * 2 + 0) * 512]);                                     \
        r_ = r0 + 8;                                                            \
        gload16(base + (size_t)r_ * ld + (kt) * 64 + ((cbs ^ (r_ & 7)) << 3),   \
                &buf[(wid * 2 + 1) * 512]);                                     \
    }

    const int lr = lane & 15, lg = lane >> 4;
    const int wr = (wid >> 1) * 32, wc = (wid & 1) * 32;
    const int mA0 = wr + lr, mA1 = wr + 16 + lr;
    const int nB0 = wc + lr, nB1 = wc + 16 + lr;
    f32x4 acc[2][2] = {};

#define COMPUTE(b)                                                              \
    _Pragma("unroll")                                                           \
    for (int kk = 0; kk < 2; ++kk) {                                            \
        const int kb = kk * 4 + lg;                                             \
        bf16x8 a0 = *(const bf16x8*)&Ab[b][mA0 * 64 + ((kb ^ (mA0 & 7)) << 3)]; \
        bf16x8 a1 = *(const bf16x8*)&Ab[b][mA1 * 64 + ((kb ^ (mA1 & 7)) << 3)]; \
        bf16x8 b0 = *(const bf16x8*)&Bb[b][nB0 * 64 + ((kb ^ (nB0 & 7)) << 3)]; \
        bf16x8 b1 = *(const bf16x8*)&Bb[b][nB1 * 64 + ((kb ^ (nB1 & 7)) << 3)]; \
        acc[0][0] = __builtin_amdgcn_mfma_f32_16x16x32_bf16(a0, b0, acc[0][0], 0, 0, 0); \
        acc[0][1] = __builtin_amdgcn_mfma_f32_16x16x32_bf16(a0, b1, acc[0][1], 0, 0, 0); \
        acc[1][0] = __builtin_amdgcn_mfma_f32_16x16x32_bf16(a1, b0, acc[1][0], 0, 0, 0); \
        acc[1][1] = __builtin_amdgcn_mfma_f32_16x16x32_bf16(a1, b1, acc[1][1], 0, 0, 0); \
    }

    STAGE_T(Ab[0], Abase, lda, 0);
    STAGE_T(Bb[0], Bbase, ldb, 0);
    __syncthreads();
    const int NT = K >> 6;
    int cur = 0;
    for (int kt = 0; kt < NT; ++kt) {
        if (kt + 1 < NT) {
            STAGE_T(Ab[cur ^ 1], Abase, lda, kt + 1);
            STAGE_T(Bb[cur ^ 1], Bbase, ldb, kt + 1);
        }
        if (cur == 0) { COMPUTE(0); } else { COMPUTE(1); }
        __syncthreads();
        cur ^= 1;
    }

#pragma unroll
    for (int fm = 0; fm < 2; ++fm)
#pragma unroll
    for (int fn = 0; fn < 2; ++fn) {
        const int col = bn + wc + fn * 16 + lr;
        float bia = BIAS ? bias[bz * sBias + col] : 0.f;
#pragma unroll
        for (int r = 0; r < 4; ++r) {
            const int row = bm + wr + fm * 16 + lg * 4 + r;
            const size_t ci = (size_t)bz * sC + (size_t)row * ldc + col;
            float v = acc[fm][fn][r] + bia;
            if (RES) v += res[(size_t)row * ldc + col];
            if (RELU) v = fmaxf(v, 0.f);
            if (WF32) Cf[ci] = v;
            if (WBF)  Cb[ci] = f2bf(v);
        }
    }
#undef STAGE_T
#undef COMPUTE
}

// ------------------------------------------------- K5: fused attention, query-paired
// Block = one pair (qa,qb) sharing memory s. Waves 0-3: scores MFMA with 16
// B-cols = {qa heads 0-7, qb heads 8-15} (enc read ONCE per pair) + softmax.
// Waves 4-7: V prefetch (concurrent with scores) + PV for both queries.
__global__ __launch_bounds__(512) void attn_fused_k(
    const unsigned short* __restrict__ u_bf, const float* __restrict__ enc,
    const float* __restrict__ vemb, const int* __restrict__ maskmem,
    const int* __restrict__ samples, const int2* __restrict__ plist,
    const int* __restrict__ npairs, unsigned* __restrict__ a_bf)
{
    __shared__ float S_lds[16 * 68];
    __shared__ uint4 P_lds[2][64];    // [query][key] -> 8 heads bf16
    __shared__ int Msk_lds[64];
    const int pid = blockIdx.x;
    if (pid >= *npairs) return;
    const int2 pq = plist[pid];
    const int qa = pq.x, qb = pq.y;
    int s = samples[qa]; if (s < 0) s = 0;
    const int t = threadIdx.x, lane = t & 63, w = t >> 6;

    float2 pfv[8];
    const float2* vb = (const float2*)(vemb + (size_t)s * (LM * DIM)) + (t - 256);

    if (w >= 4) {
        // PV waves: thread owns dim-pair (t-256); prefetch keys 0..7
#pragma unroll
        for (int i = 0; i < 8; ++i) pfv[i] = vb[(size_t)i * 256];
        if (w == 4) Msk_lds[lane] = maskmem[(size_t)s * LM + lane];
    } else {
        // scores waves: wave w -> keys [w*16, w*16+16), full K=512 in 16 steps
        const float4* kb = (const float4*)(enc + (size_t)s * (LM * DIM));
        const int key = w * 16 + (lane & 15);
        const int lg = lane >> 4;
        const int h = lane & 15;
        const int base = key * 128 + lg * 2;  // float4 units
        float4 pf[4][2];
#pragma unroll
        for (int ss = 0; ss < 4; ++ss) {
            pf[ss][0] = kb[base + ss * 8];
            pf[ss][1] = kb[base + ss * 8 + 1];
        }
        const int qsel = (h < 8) ? qa : qb;
        const unsigned short* ub = u_bf + (size_t)qsel * 4096 + (size_t)(h & 7) * 512;
        f32x4 acc = {};
#pragma unroll
        for (int step = 0; step < 16; ++step) {
            float4 a0 = pf[step & 3][0], a1 = pf[step & 3][1];
            if (step + 4 < 16) {
                pf[step & 3][0] = kb[base + (step + 4) * 8];
                pf[step & 3][1] = kb[base + (step + 4) * 8 + 1];
            }
            bf16x8 af;
            af[0] = (__bf16)a0.x; af[1] = (__bf16)a0.y;
            af[2] = (__bf16)a0.z; af[3] = (__bf16)a0.w;
            af[4] = (__bf16)a1.x; af[5] = (__bf16)a1.y;
            af[6] = (__bf16)a1.z; af[7] = (__bf16)a1.w;
            bf16x8 bfr = *(const bf16x8*)&ub[(step * 4 + lg) * 8];
            acc = __builtin_amdgcn_mfma_f32_16x16x32_bf16(af, bfr, acc, 0, 0, 0);
        }
#pragma unroll
        for (int r = 0; r < 4; ++r)
            S_lds[h * 68 + w * 16 + lg * 4 + r] = acc[r];
    }
    __syncthreads();   // S_lds + Msk ready

    if (w < 4) {
        // softmax: 16 slots (2 queries x 8 heads); wave w -> slots w, w+4, w+8, w+12
#pragma unroll
        for (int i = 0; i < 4; ++i) {
            const int slot = w + i * 4;
            const int qq = slot >> 3, h2 = slot & 7;
            float sc = S_lds[slot * 68 + lane] * 0.125f;
            sc = (Msk_lds[lane] != 0) ? sc : -1e9f;
            float m = sc;
#pragma unroll
            for (int o = 32; o; o >>= 1) m = fmaxf(m, __shfl_xor(m, o));
            float e = __expf(sc - m);
            float su = e;
#pragma unroll
            for (int o = 32; o; o >>= 1) su += __shfl_xor(su, o);
            ((unsigned short*)P_lds)[(qq * 64 + lane) * 8 + h2] = f2bf(e / su);
        }
    }
    __syncthreads();   // P ready

    if (w >= 4) {
        float2 accA[8], accB[8];
#pragma unroll
        for (int hh = 0; hh < 8; ++hh) {
            accA[hh] = make_float2(0.f, 0.f);
            accB[hh] = make_float2(0.f, 0.f);
        }
#pragma unroll 8
        for (int k = 0; k < 64; ++k) {
            float2 v = pfv[k & 7];
            if (k + 8 < 64) pfv[k & 7] = vb[(size_t)(k + 8) * 256];
            uint4 pa = P_lds[0][k];
            uint4 pb = P_lds[1][k];
            float a0 = bflo(pa.x), a1 = bfhi(pa.x), a2 = bflo(pa.y), a3 = bfhi(pa.y);
            float a4 = bflo(pa.z), a5 = bfhi(pa.z), a6 = bflo(pa.w), a7 = bfhi(pa.w);
            float b0 = bflo(pb.x), b1 = bfhi(pb.x), b2 = bflo(pb.y), b3 = bfhi(pb.y);
            float b4 = bflo(pb.z), b5 = bfhi(pb.z), b6 = bflo(pb.w), b7 = bfhi(pb.w);
            accA[0].x = fmaf(a0, v.x, accA[0].x); accA[0].y = fmaf(a0, v.y, accA[0].y);
            accA[1].x = fmaf(a1, v.x, accA[1].x); accA[1].y = fmaf(a1, v.y, accA[1].y);
            accA[2].x = fmaf(a2, v.x, accA[2].x); accA[2].y = fmaf(a2, v.y, accA[2].y);
            accA[3].x = fmaf(a3, v.x, accA[3].x); accA[3].y = fmaf(a3, v.y, accA[3].y);
            accA[4].x = fmaf(a4, v.x, accA[4].x); accA[4].y = fmaf(a4, v.y, accA[4].y);
            accA[5].x = fmaf(a5, v.x, accA[5].x); accA[5].y = fmaf(a5, v.y, accA[5].y);
            accA[6].x = fmaf(a6, v.x, accA[6].x); accA[6].y = fmaf(a6, v.y, accA[6].y);
            accA[7].x = fmaf(a7, v.x, accA[7].x); accA[7].y = fmaf(a7, v.y, accA[7].y);
            accB[0].x = fmaf(b0, v.x, accB[0].x); accB[0].y = fmaf(b0, v.y, accB[0].y);
            accB[1].x = fmaf(b1, v.x, accB[1].x); accB[1].y = fmaf(b1, v.y, accB[1].y);
            accB[2].x = fmaf(b2, v.x, accB[2].x); accB[2].y = fmaf(b2, v.y, accB[2].y);
            accB[3].x = fmaf(b3, v.x, accB[3].x); accB[3].y = fmaf(b3, v.y, accB[3].y);
            accB[4].x = fmaf(b4, v.x, accB[4].x); accB[4].y = fmaf(b4, v.y, accB[4].y);
            accB[5].x = fmaf(b5, v.x, accB[5].x); accB[5].y = fmaf(b5, v.y, accB[5].y);
            accB[6].x = fmaf(b6, v.x, accB[6].x); accB[6].y = fmaf(b6, v.y, accB[6].y);
            accB[7].x = fmaf(b7, v.x, accB[7].x); accB[7].y = fmaf(b7, v.y, accB[7].y);
        }
        unsigned* an = a_bf + (size_t)qa * 2048 + (t - 256);
#pragma unroll
        for (int hh = 0; hh < 8; ++hh)
            an[hh * 256] = (unsigned)f2bf(accA[hh].x) | ((unsigned)f2bf(accA[hh].y) << 16);
        if (qb != qa) {
            unsigned* bn2 = a_bf + (size_t)qb * 2048 + (t - 256);
#pragma unroll
            for (int hh = 0; hh < 8; ++hh)
                bn2[hh * 256] = (unsigned)f2bf(accB[hh].x) | ((unsigned)f2bf(accB[hh].y) << 16);
        }
    }
}

// ------------------------------------------------- K10: combine T1 parts + LN + mask + x
__global__ __launch_bounds__(256) void ln1_mask_add_k(
    const float* __restrict__ t1p, const float* __restrict__ st0,
    const float* __restrict__ b2, const float* __restrict__ g,
    const float* __restrict__ be, const int* __restrict__ samples,
    const float* __restrict__ x, float* __restrict__ dec, unsigned* __restrict__ decb)
{
    __shared__ float red[4];
    const int n = blockIdx.x, t = threadIdx.x;
    const size_t off = (size_t)n * DIM + t * 2;
    float2 p0 = *(const float2*)&t1p[off];
    float2 p1 = *(const float2*)&t1p[(size_t)NQ * DIM + off];
    float2 s0 = *(const float2*)&st0[off];
    float2 b2v = ((const float2*)b2)[t];
    float2 v = make_float2(p0.x + p1.x + s0.x + b2v.x, p0.y + p1.y + s0.y + b2v.y);
    float mu  = blk_sum(v.x + v.y, red) * (1.f / DIM);
    float dx = v.x - mu, dy = v.y - mu;
    float var = blk_sum(dx * dx + dy * dy, red) * (1.f / DIM);
    float rs = rsqrtf(var + 1e-5f);
    float2 gg = ((const float2*)g)[t], bb = ((const float2*)be)[t];
    float sx = dx * rs * gg.x + bb.x, sy = dy * rs * gg.y + bb.y;
    if (samples[n] < 0) { sx = 0.f; sy = 0.f; }
    float2 xx = *(const float2*)&x[off];
    float ox = xx.x + sx, oy = xx.y + sy;
    *(float2*)&dec[off] = make_float2(ox, oy);
    decb[(size_t)n * 256 + t] = (unsigned)f2bf(ox) | ((unsigned)f2bf(oy) << 16);
}

// ---------------------------------------------------------------- launcher
extern "C" void kernel_launch(void* const* d_in, const int* in_sizes, int n_in,
                              void* d_out, int out_size, void* d_ws, size_t ws_size,
                              hipStream_t stream)
{
    const float* dec_output = (const float*)d_in[0];
    const float* mem_attn   = (const float*)d_in[1];
    const float* enc_mem    = (const float*)d_in[2];
    const float* temb_mem   = (const float*)d_in[3];
    const int*   mask_mem   = (const int*)d_in[4];
    const float* g0  = (const float*)d_in[6];
    const float* be0 = (const float*)d_in[7];
    const float* g1  = (const float*)d_in[8];
    const float* be1 = (const float*)d_in[9];
    const float* Wq  = (const float*)d_in[10];
    const float* bq  = (const float*)d_in[11];
    const float* Wk  = (const float*)d_in[12];
    const float* Wv  = (const float*)d_in[14];
    const float* bv  = (const float*)d_in[15];
    const float* Wo  = (const float*)d_in[16];
    const float* bo  = (const float*)d_in[17];
    const float* f1W1 = (const float*)d_in[18];
    const float* f1b1 = (const float*)d_in[19];
    const float* f1W2 = (const float*)d_in[20];
    const float* f1b2 = (const float*)d_in[21];
    const float* f2W1 = (const float*)d_in[22];
    const float* f2b1 = (const float*)d_in[23];
    const float* f2W2 = (const float*)d_in[24];
    const float* f2b2 = (const float*)d_in[25];
    float* out = (float*)d_out;

    float* ws = (float*)d_ws;
    // persistent (offsets in floats)
    float*          x_f   = ws + 0;                          // 524288
    unsigned*       x_b   = (unsigned*)(ws + 524288);        // 262144
    unsigned short* qh_b  = (unsigned short*)(ws + 786432);  // 262144
    unsigned short* u_b   = (unsigned short*)(ws + 1048576); // 2097152
    unsigned short* a_b   = (unsigned short*)(ws + 3145728); // 2097152
    unsigned short* wqt   = (unsigned short*)(ws + 7340032); // 131072 each
    unsigned short* wkc   = (unsigned short*)(ws + 7471104);
    unsigned short* wvt   = (unsigned short*)(ws + 7602176);
    unsigned short* wot   = (unsigned short*)(ws + 7733248);
    unsigned short* f1w1t = (unsigned short*)(ws + 7864320); // 524288 each
    unsigned short* f1w2t = (unsigned short*)(ws + 8388608);
    unsigned short* f2w1t = (unsigned short*)(ws + 8912896);
    unsigned short* f2w2t = (unsigned short*)(ws + 9437184);
    int*            smp   = (int*)(ws + 9961472);            // 1024
    float*          t1p_f = ws + 9962496;                    // 1048576 (2 parts)
    int2*           plist = (int2*)(ws + 11011072);          // 1024 int2
    int*            npair = (int*)(ws + 11013120);           // 1
    // aliases inside u_b region (u dead after attn_fused):
    float*          st0_f = (float*)u_b + 0;                 // 524288
    unsigned short* st0_b = (unsigned short*)((float*)u_b + 524288); // 131072
    float*          dec_f = (float*)u_b + 655360;            // 524288
    unsigned*       dec_b = (unsigned*)((float*)u_b + 1179648); // 131072
    // aliases inside a_b region (a dead after CTX GEMM):
    unsigned short* h1_b  = a_b;                             // 1024x2048 bf16
    unsigned short* h2_b  = (unsigned short*)((float*)a_b + 1048576);

    PrepPtrs pp;
    pp.src[0] = Wq;   pp.dst[0] = wqt;
    pp.src[1] = Wk;   pp.dst[1] = wkc;
    pp.src[2] = Wv;   pp.dst[2] = wvt;
    pp.src[3] = Wo;   pp.dst[3] = wot;
    pp.src[4] = f1W1; pp.dst[4] = f1w1t;
    pp.src[5] = f1W2; pp.dst[5] = f1w2t;
    pp.src[6] = f2W1; pp.dst[6] = f2w1t;
    pp.src[7] = f2W2; pp.dst[7] = f2w2t;
    // 1. weight prep + LN0 + argmax
    prep_ln0_k<<<5120 + NQ, 256, 0, stream>>>(pp, dec_output, mem_attn, g0, be0,
                                              x_f, x_b, smp);
    // 2. build same-memory query pairs
    group_build_k<<<1, 1024, 0, stream>>>(smp, plist, npair);
    // 3. QH = X @ Wq + bq  (bf16 out only)
    mfma_gemm<false, true, false, false, true><<<dim3(8, 16, 1), 256, 0, stream>>>(
        (const unsigned short*)x_b, wqt, nullptr, qh_b, bq, nullptr,
        DIM, DIM, DIM, DIM, 0, 0, 0, 0);
    // 4. U_h = QH_h @ Wk_h^T (batched heads, K=64)
    mfma_gemm<false, false, false, false, true><<<dim3(8, 16, NH), 256, 0, stream>>>(
        qh_b, wkc, nullptr, u_b, nullptr, nullptr,
        DHD, DIM, DIM, NH * DIM, DHD, DHD, DIM, 0);
    // 5. fused attention (query-paired; scores + softmax + PV, wave-specialized)
    attn_fused_k<<<NQ, 512, 0, stream>>>(u_b, enc_mem, temb_mem, mask_mem, smp,
                                         plist, npair, (unsigned*)a_b);
    // 6. CTX_h = A_h @ Wv_h + bv_h
    mfma_gemm<false, true, false, false, true><<<dim3(1, 16, NH), 256, 0, stream>>>(
        a_b, wvt, nullptr, qh_b, bv, nullptr,
        DIM, NH * DIM, DIM, DIM, DIM, DHD * DIM, DHD, DHD);
    // 7. ST0 = X + CTX @ Wo + bo
    mfma_gemm<false, true, true, true, true><<<dim3(8, 16, 1), 256, 0, stream>>>(
        qh_b, wot, st0_f, st0_b, bo, x_f, DIM, DIM, DIM, DIM, 0, 0, 0, 0);
    // 8. H1 = relu(ST0 @ f1W1 + f1b1)
    mfma_gemm<true, true, false, false, true><<<dim3(32, 16, 1), 256, 0, stream>>>(
        st0_b, f1w1t, nullptr, h1_b, f1b1, nullptr, DIM, DIM, DIM, DFF, 0, 0, 0, 0);
    // 9. T1 parts = H1 @ f1W2 (split-K=2; bias/res merged in LN1)
    mfma_gemm<false, false, false, true, false><<<dim3(8, 16, 2), 256, 0, stream>>>(
        h1_b, f1w2t, t1p_f, nullptr, nullptr, nullptr,
        1024, DFF, DFF, DIM, 1024, 1024, NQ * DIM, 0);
    // 10. DEC = X + mask * LN1(p0 + p1 + ST0 + f1b2)
    ln1_mask_add_k<<<NQ, 256, 0, stream>>>(t1p_f, st0_f, f1b2, g1, be1, smp,
                                           x_f, dec_f, dec_b);
    // 11. H2 = relu(DEC @ f2W1 + f2b1)
    mfma_gemm<true, true, false, false, true><<<dim3(32, 16, 1), 256, 0, stream>>>(
        (const unsigned short*)dec_b, f2w1t, nullptr, h2_b, f2b1, nullptr,
        DIM, DIM, DIM, DFF, 0, 0, 0, 0);
    // 12. OUT = DEC + H2 @ f2W2 + f2b2
    mfma_gemm<false, true, true, true, false><<<dim3(8, 16, 1), 256, 0, stream>>>(
        h2_b, f2w2t, out, nullptr, f2b2, dec_f, DFF, DFF, DFF, DIM, 0, 0, 0, 0);

    (void)in_sizes; (void)n_in; (void)out_size; (void)ws_size;
}